// Round 4
// baseline (180.358 us; speedup 1.0000x reference)
//
#include <hip/hip_runtime.h>

// Problem constants (from reference): B=16384, D=255, K=4, L=16, T=1020
constexpr int T_TUN = 1020;
constexpr int D_DST = 255;
constexpr int L_LNK = 16;
constexpr float EPS = 1e-8f;
constexpr int ROWS_PER_BLOCK = 8;   // 4 waves x 2 rows
constexpr int ROWS_PER_WAVE  = 2;

__device__ __forceinline__ float read_lane_f(float v, int l) {
  return __builtin_bit_cast(float,
      __builtin_amdgcn_readlane(__builtin_bit_cast(int, v), l));
}

__global__ __launch_bounds__(256) void rowloss_kernel(
    const float* __restrict__ pred,     // [B, T]
    const float* __restrict__ demands,  // [B, D]
    const float* __restrict__ cur,      // [B, L]
    const float* __restrict__ caps,     // [L]
    const int*   __restrict__ t2l,      // [T]
    float* __restrict__ out, float invB)
{
  const int tid  = threadIdx.x;
  const int lane = tid & 63;
  const int w    = tid >> 6;   // wave id 0..3

  // Bin-major per-lane bins: priv[bin*64 + lane].
  //  - scatter (ds_add_f32): bank = lane&31 -> conflict-free
  //  - column reduce with rotated region walk -> 2-way only (free)
  __shared__ float priv_all[4][L_LNK * 64];
  __shared__ float wacc[4];
  float* priv = priv_all[w];

  const int b16 = lane & 15;       // this lane's bin for the reduce/stats
  const int g   = lane >> 4;       // lane group 0..3
  const float capinv = 1.0f / (caps[b16] + EPS);

  // Row-invariant scatter offsets: element index = link*64 + lane
  int off[4][4];
  bool dv[4];
#pragma unroll
  for (int j = 0; j < 4; ++j) {
    const int d = lane + 64 * j;
    dv[j] = (d < D_DST);
    const int dd = dv[j] ? d : 0;
    const int4 lk = ((const int4*)t2l)[dd];   // t2l[4d..4d+3]
    off[j][0] = lk.x * 64 + lane;
    off[j][1] = lk.y * 64 + lane;
    off[j][2] = lk.z * 64 + lane;
    off[j][3] = lk.w * 64 + lane;
  }

  // reduce base: bin b16, regions 16g + ((k + b16) & 15)
  const int rbase = b16 * 64 + g * 16;

  float acc = 0.0f;
  const int row0 = blockIdx.x * ROWS_PER_BLOCK + w * ROWS_PER_WAVE;

#pragma unroll
  for (int r = 0; r < ROWS_PER_WAVE; ++r) {
    const int b = row0 + r;

    __builtin_amdgcn_wave_barrier();  // keep zero-writes after prior row's reads

    // zero the wave's 1024-float region: 4x ds_write_b128 per lane
    {
      const float4 z = make_float4(0.f, 0.f, 0.f, 0.f);
      float4* pz = (float4*)priv;
#pragma unroll
      for (int i = 0; i < 4; ++i) pz[lane + 64 * i] = z;
    }

    const float  mycur = cur[(size_t)b * L_LNK + b16];
    const float4* prow = (const float4*)(pred + (size_t)b * T_TUN);
    const float*  drow = demands + (size_t)b * D_DST;

    // scatter: native ds_add_f32 into lane-distinct slots (no contention)
#pragma unroll
    for (int j = 0; j < 4; ++j) {
      if (!dv[j]) continue;            // only lane63/j3 diverges
      const int d = lane + 64 * j;
      const float4 r4 = prow[d];       // ratios for tunnels 4d..4d+3
      const float dem = drow[d];       // demand shared by the 4 tunnels
      unsafeAtomicAdd(&priv[off[j][0]], r4.x * dem);
      unsafeAtomicAdd(&priv[off[j][1]], r4.y * dem);
      unsafeAtomicAdd(&priv[off[j][2]], r4.z * dem);
      unsafeAtomicAdd(&priv[off[j][3]], r4.w * dem);
    }

    __builtin_amdgcn_wave_barrier();  // keep reduce reads after scatter adds

    // column reduce: lane sums its bin over 16 regions (rotated -> 2-way banks)
    float cs = 0.0f;
#pragma unroll
    for (int k = 0; k < 16; ++k) cs += priv[rbase + ((k + b16) & 15)];
    // fold the 4 lane-groups -> every lane holds full bins[b16]
    cs += __shfl_xor(cs, 16, 64);
    cs += __shfl_xor(cs, 32, 64);

    const float u = cs * capinv;

    // fused stats: group 0 sums u, group 1 sums u^2, group 2 sums u*cur,
    // group 3 maxes u. One butterfly instead of four.
    float val = (g == 0) ? u : (g == 1) ? (u * u) : (g == 2) ? (u * mycur) : u;
#pragma unroll
    for (int m = 1; m < 16; m <<= 1) {
      const float o  = __shfl_xor(val, m, 64);
      const float sm = val + o;
      const float mm = fmaxf(val, o);
      val = (g == 3) ? mm : sm;
    }
    const float s1 = read_lane_f(val, 0);
    const float s2 = read_lane_f(val, 16);
    const float s3 = read_lane_f(val, 32);
    const float mx = read_lane_f(val, 48);

    const float var = (s2 - s1 * s1 * (1.0f / 16.0f)) * (1.0f / 15.0f); // ddof=1
    acc += 0.3f * var + 0.5f * s3 + 0.2f * mx;
  }

  if (lane == 0) wacc[w] = acc;
  __syncthreads();
  if (tid == 0) atomicAdd(out, (wacc[0] + wacc[1] + wacc[2] + wacc[3]) * invB);
}

__global__ void zero_out_kernel(float* __restrict__ out) { out[0] = 0.0f; }

extern "C" void kernel_launch(void* const* d_in, const int* in_sizes, int n_in,
                              void* d_out, int out_size, void* d_ws, size_t ws_size,
                              hipStream_t stream) {
  const float* pred    = (const float*)d_in[0];  // [B, T]
  const float* demands = (const float*)d_in[1];  // [B, D]
  const float* cur     = (const float*)d_in[2];  // [B, L]
  const float* caps    = (const float*)d_in[3];  // [L]
  const int*   t2l     = (const int*)d_in[4];    // [T]
  float* out = (float*)d_out;

  const int L = in_sizes[3];          // 16
  const int B = in_sizes[2] / L;      // 16384

  const int grid = B / ROWS_PER_BLOCK;  // 2048

  zero_out_kernel<<<1, 1, 0, stream>>>(out);
  rowloss_kernel<<<grid, 256, 0, stream>>>(pred, demands, cur, caps, t2l,
                                           out, 1.0f / (float)B);
}

// Round 5
// 122.915 us; speedup vs baseline: 1.4673x; 1.4673x over previous
//
#include <hip/hip_runtime.h>

// Problem constants (from reference): B=16384, D=255, K=4, L=16, T=1020
constexpr int T_TUN = 1020;
constexpr int D_DST = 255;
constexpr int L_LNK = 16;
constexpr float EPS = 1e-8f;
constexpr int ROWS_PER_BLOCK = 8;   // 4 waves x 2 rows

__device__ __forceinline__ float read_lane_f(float v, int l) {
  return __builtin_bit_cast(float,
      __builtin_amdgcn_readlane(__builtin_bit_cast(int, v), l));
}

__global__ __launch_bounds__(256) void rowloss_kernel(
    const float* __restrict__ pred,     // [B, T]
    const float* __restrict__ demands,  // [B, D]
    const float* __restrict__ cur,      // [B, L]
    const float* __restrict__ caps,     // [L]
    const int*   __restrict__ t2l,      // [T]
    float* __restrict__ out, float invB)
{
  const int tid  = threadIdx.x;
  const int lane = tid & 63;
  const int w    = tid >> 6;   // wave id 0..3

  // Bin-major per-lane bins, ONE REGION PER ROW so the two rows' RMW chains
  // are independent (offsets masked &1023 so AA can prove region separation).
  // element index within region = link*64 + lane  -> bank = lane&31, no conflicts
  __shared__ float priv_all[4][2][64 * L_LNK];
  __shared__ float wacc[4];

  const int b16 = lane & 15;       // this lane's bin for the reduce/stats
  const int g   = lane >> 4;       // lane group 0..3
  const float capinv = 1.0f / (caps[b16] + EPS);

  // Row-invariant scatter offsets
  int off[4][4];
  bool dv[4];
#pragma unroll
  for (int j = 0; j < 4; ++j) {
    const int d = lane + 64 * j;
    dv[j] = (d < D_DST);
    const int dd = dv[j] ? d : 0;
    const int4 lk = ((const int4*)t2l)[dd];   // t2l[4d..4d+3]
    off[j][0] = (lk.x * 64 + lane) & 1023;
    off[j][1] = (lk.y * 64 + lane) & 1023;
    off[j][2] = (lk.z * 64 + lane) & 1023;
    off[j][3] = (lk.w * 64 + lane) & 1023;
  }

  const int row0 = blockIdx.x * ROWS_PER_BLOCK + w * 2;

  // ---- issue ALL global loads for both rows up front (max MLP) ----
  float4 r4[2][4];
  float  dm[2][4];
  float  mycur[2];
#pragma unroll
  for (int r = 0; r < 2; ++r) {
    const int b = row0 + r;
    const float4* prow = (const float4*)(pred + (size_t)b * T_TUN);
    const float*  drow = demands + (size_t)b * D_DST;
    mycur[r] = cur[(size_t)b * L_LNK + b16];
#pragma unroll
    for (int j = 0; j < 4; ++j) {
      const int d = lane + 64 * j;
      if (dv[j]) { r4[r][j] = prow[d]; dm[r][j] = drow[d]; }
    }
  }

  // ---- zero both regions: 8x ds_write_b128 ----
  {
    const float4 z = make_float4(0.f, 0.f, 0.f, 0.f);
#pragma unroll
    for (int r = 0; r < 2; ++r) {
      float4* pz = (float4*)priv_all[w][r];
#pragma unroll
      for (int i = 0; i < 4; ++i) pz[lane + 64 * i] = z;
    }
  }

  // ---- scatter: plain RMW, rows interleaved (2 independent alias domains) ----
#pragma unroll
  for (int j = 0; j < 4; ++j) {
    if (!dv[j]) continue;            // only lane63/j3 diverges
#pragma unroll
    for (int r = 0; r < 2; ++r) {
      const float4 v = r4[r][j];
      const float  d = dm[r][j];
      priv_all[w][r][off[j][0]] += v.x * d;
      priv_all[w][r][off[j][1]] += v.y * d;
      priv_all[w][r][off[j][2]] += v.z * d;
      priv_all[w][r][off[j][3]] += v.w * d;
    }
  }

  // ---- column reduce (rotated walk -> 2-way banks, free) + stats ----
  const int rbase = b16 * 64 + g * 16;
  float acc = 0.0f;
  float cs[2] = {0.0f, 0.0f};
#pragma unroll
  for (int k = 0; k < 16; ++k) {
    const int idx = (rbase + ((k + b16) & 15)) & 1023;
#pragma unroll
    for (int r = 0; r < 2; ++r) cs[r] += priv_all[w][r][idx];
  }
#pragma unroll
  for (int r = 0; r < 2; ++r) {
    cs[r] += __shfl_xor(cs[r], 16, 64);
    cs[r] += __shfl_xor(cs[r], 32, 64);
  }

  // fused stats: group 0 sums u, group 1 sums u^2, group 2 sums u*cur,
  // group 3 maxes u. One butterfly per row.
  float val[2];
#pragma unroll
  for (int r = 0; r < 2; ++r) {
    const float u = cs[r] * capinv;
    val[r] = (g == 0) ? u : (g == 1) ? (u * u) : (g == 2) ? (u * mycur[r]) : u;
  }
#pragma unroll
  for (int m = 1; m < 16; m <<= 1) {
#pragma unroll
    for (int r = 0; r < 2; ++r) {
      const float o  = __shfl_xor(val[r], m, 64);
      const float sm = val[r] + o;
      const float mm = fmaxf(val[r], o);
      val[r] = (g == 3) ? mm : sm;
    }
  }
#pragma unroll
  for (int r = 0; r < 2; ++r) {
    const float s1 = read_lane_f(val[r], 0);
    const float s2 = read_lane_f(val[r], 16);
    const float s3 = read_lane_f(val[r], 32);
    const float mx = read_lane_f(val[r], 48);
    const float var = (s2 - s1 * s1 * (1.0f / 16.0f)) * (1.0f / 15.0f); // ddof=1
    acc += 0.3f * var + 0.5f * s3 + 0.2f * mx;
  }

  if (lane == 0) wacc[w] = acc;
  __syncthreads();
  if (tid == 0) atomicAdd(out, (wacc[0] + wacc[1] + wacc[2] + wacc[3]) * invB);
}

__global__ void zero_out_kernel(float* __restrict__ out) { out[0] = 0.0f; }

extern "C" void kernel_launch(void* const* d_in, const int* in_sizes, int n_in,
                              void* d_out, int out_size, void* d_ws, size_t ws_size,
                              hipStream_t stream) {
  const float* pred    = (const float*)d_in[0];  // [B, T]
  const float* demands = (const float*)d_in[1];  // [B, D]
  const float* cur     = (const float*)d_in[2];  // [B, L]
  const float* caps    = (const float*)d_in[3];  // [L]
  const int*   t2l     = (const int*)d_in[4];    // [T]
  float* out = (float*)d_out;

  const int L = in_sizes[3];          // 16
  const int B = in_sizes[2] / L;      // 16384

  const int grid = B / ROWS_PER_BLOCK;  // 2048

  zero_out_kernel<<<1, 1, 0, stream>>>(out);
  rowloss_kernel<<<grid, 256, 0, stream>>>(pred, demands, cur, caps, t2l,
                                           out, 1.0f / (float)B);
}